// Round 6
// baseline (185.497 us; speedup 1.0000x reference)
//
#include <hip/hip_runtime.h>
#include <math.h>

#define H_ 1024
#define W_ 2048
#define HW_ (H_ * W_)
#define NB_ 2048                           // half-row per block
#define TPB_ 128
#define HALF_ 1024

#define FLUXF     0.87890625f              // 300*(6/2048)
#define F_FACT    0.002574920654296875f    // 300*(6/2048)^2
#define WC0VF     65.96910698f             // 651.83*202.412*0.001/2
#define POROUS_K  0.521986224f             // C1*C2*C4*CT

// b after the sequential .at[].set() chain (later writes win):
//   b[0,:]=3, b[-1,:]=3 ; b[:,-1]=3 ; b[:,1]=0 ; b[1,1:]=0, b[-2,1:]=0 (j>=1!)
__device__ __forceinline__ int fix_b(int raw, int i, int j) {
    if (i == 0 || i == H_ - 1) return 3;
    if (j == W_ - 1) return 3;
    if (j == 1) return 0;
    if ((i == 1 || i == H_ - 2) && j >= 1) return 0;
    return raw;
}

// Half-row per block, 8 px/thread. Moments (quadratic-in-porous split):
//  s0=sum(wc_bc) s1=sum(a^2) s2=sum(a*c) s3=sum(c^2)
//  s4=sum(aw^2)  s5=sum(aw*q) s6=sum(q^2);  e=a+p*c, w=aw-p*q.
// Last-finished block reduces the 7*NB_ partials and writes out[0].
__global__ __launch_bounds__(TPB_)
void k_main(const int* __restrict__ layout, const float* __restrict__ heat_ini,
            const float* __restrict__ wc, const float* __restrict__ heat,
            const float* __restrict__ flow, float* __restrict__ out_hb,
            float* __restrict__ out_eq, float* __restrict__ ws,
            float* __restrict__ out) {
    // XCD-strip swizzle: XCD x owns rows [x*128, (x+1)*128).
    const int virt = ((blockIdx.x & 7) << 8) | (blockIdx.x >> 3);
    const int i    = virt >> 1;
    const int jb0  = (virt & 1) * HALF_;
    const int tid  = threadIdx.x;
    const int lj   = tid << 3;
    const int jb   = jb0 + lj;
    const int im = (i == 0) ? 1 : i - 1;
    const int ip = (i == H_ - 1) ? H_ - 2 : i + 1;
    const int* L1 = layout + HW_;
    const int base  = i * W_ + jb;
    const int baseu = im * W_ + jb;
    const int based = ip * W_ + jb;

    int4   bc0 = *(const int4*)(L1 + base),      bc1 = *(const int4*)(L1 + base + 4);
    int4   bu0 = *(const int4*)(L1 + baseu),     bu1 = *(const int4*)(L1 + baseu + 4);
    int4   bd0 = *(const int4*)(L1 + based),     bd1 = *(const int4*)(L1 + based + 4);
    int4   g0  = *(const int4*)(layout + base),  g1  = *(const int4*)(layout + base + 4);
    float4 hc0 = *(const float4*)(heat + base),  hc1 = *(const float4*)(heat + base + 4);
    float4 hu0 = *(const float4*)(heat + baseu), hu1 = *(const float4*)(heat + baseu + 4);
    float4 hd0 = *(const float4*)(heat + based), hd1 = *(const float4*)(heat + based + 4);
    float4 hi0 = *(const float4*)(heat_ini + base), hi1 = *(const float4*)(heat_ini + base + 4);
    float4 w0  = *(const float4*)(wc + base),    w1  = *(const float4*)(wc + base + 4);
    float4 u0  = *(const float4*)(flow + base),  u1  = *(const float4*)(flow + base + 4);
    float4 v0  = *(const float4*)(flow + HW_ + base), v1 = *(const float4*)(flow + HW_ + base + 4);

    // Block-edge halo (masked heat_bc just outside this half-row)
    __shared__ float shb[HALF_ + 2];       // shb[x+1] = masked local x
    if (tid == 0) {
        float hv = 0.0f;
        if (jb0 != 0) {
            int j = jb0 - 1;
            hv = (fix_b(L1[i * W_ + j], i, j) != 1) ? heat[i * W_ + j] : 0.0f;
        }
        shb[0] = hv;
    }
    if (tid == TPB_ - 1) {
        float hv = 0.0f;
        if (jb0 + HALF_ < W_) {
            int j = jb0 + HALF_;
            hv = (fix_b(L1[i * W_ + j], i, j) != 1) ? heat[i * W_ + j] : 0.0f;
        }
        shb[HALF_ + 1] = hv;
    }

    int   bcs[8] = {bc0.x,bc0.y,bc0.z,bc0.w, bc1.x,bc1.y,bc1.z,bc1.w};
    int   bus[8] = {bu0.x,bu0.y,bu0.z,bu0.w, bu1.x,bu1.y,bu1.z,bu1.w};
    int   bds[8] = {bd0.x,bd0.y,bd0.z,bd0.w, bd1.x,bd1.y,bd1.z,bd1.w};
    int   gs[8]  = {g0.x,g0.y,g0.z,g0.w, g1.x,g1.y,g1.z,g1.w};
    float hcs[8] = {hc0.x,hc0.y,hc0.z,hc0.w, hc1.x,hc1.y,hc1.z,hc1.w};
    float hus[8] = {hu0.x,hu0.y,hu0.z,hu0.w, hu1.x,hu1.y,hu1.z,hu1.w};
    float hds[8] = {hd0.x,hd0.y,hd0.z,hd0.w, hd1.x,hd1.y,hd1.z,hd1.w};
    float his[8] = {hi0.x,hi0.y,hi0.z,hi0.w, hi1.x,hi1.y,hi1.z,hi1.w};
    float wss[8] = {w0.x,w0.y,w0.z,w0.w, w1.x,w1.y,w1.z,w1.w};
    float us[8]  = {u0.x,u0.y,u0.z,u0.w, u1.x,u1.y,u1.z,u1.w};
    float vs[8]  = {v0.x,v0.y,v0.z,v0.w, v1.x,v1.y,v1.z,v1.w};

    int   bfix[8];
    float hb8[8], oeqs[8];
    #pragma unroll
    for (int k = 0; k < 8; k++) {
        int b = fix_b(bcs[k], i, jb + k);
        bfix[k] = b;
        hb8[k]  = (b != 1) ? hcs[k] : 0.0f;
        oeqs[k] = (b == 1) ? 0.0f : (float)b;
    }
    *(float4*)(shb + 1 + lj)     = make_float4(hb8[0], hb8[1], hb8[2], hb8[3]);
    *(float4*)(shb + 1 + lj + 4) = make_float4(hb8[4], hb8[5], hb8[6], hb8[7]);
    *(float4*)(out_hb + base)     = make_float4(hb8[0], hb8[1], hb8[2], hb8[3]);
    *(float4*)(out_hb + base + 4) = make_float4(hb8[4], hb8[5], hb8[6], hb8[7]);
    *(float4*)(out_eq + base)     = make_float4(oeqs[0], oeqs[1], oeqs[2], oeqs[3]);
    *(float4*)(out_eq + base + 4) = make_float4(oeqs[4], oeqs[5], oeqs[6], oeqs[7]);
    __syncthreads();

    float acc[7] = {0.f,0.f,0.f,0.f,0.f,0.f,0.f};
    #pragma unroll
    for (int k = 0; k < 8; k++) {
        int j = jb + k;
        int b = bfix[k];
        float hl = (k == 0) ? shb[lj]     : hb8[k - 1];
        float hr = (k == 7) ? shb[lj + 9] : hb8[k + 1];
        float dx = (j == 0 || j == W_ - 1) ? 0.0f : 0.5f * (hr - hl);
        float hbu = (fix_b(bus[k], im, j) != 1) ? hus[k] : 0.0f;
        float hbd = (fix_b(bds[k], ip, j) != 1) ? hds[k] : 0.0f;
        float dy = 0.5f * (hbd - hbu);                  // auto-0 at i=0/H-1

        float ad = his[k] - 0.001f * (us[k] * dx + vs[k] * dy);

        float t  = hb8[k] + 273.15f;
        float t2 = t * t, t3 = t2 * t;
        float cp_a = (28.11f + 0.001967f * t + 4.802e-6f * t2 - 1.966e-9f * t3)
                     * (1000.0f / 28.97f);
        float cp_v = (32.24f + 0.001923f * t + 1.055e-5f * t2 - 3.595e-9f * t3)
                     * (1000.0f / 18.015f);
        float P_v = __expf(23.2f - __fdividef(3816.4f, t - 46.1f));
        float x_v = 0.62198f * __fdividef(P_v, 101325.0f - P_v);
        float q = __fdividef(300.0f, cp_a + cp_v * 0.00725f) * (x_v - 0.00725f);

        float f = (i == 0 || i == H_ - 1) ? 0.0f
                  : fabsf((float)gs[k] - 1.0f) * F_FACT;

        float a_e, c_e;
        if (b == 1) {
            a_e = -f; c_e = 0.0f;
        } else {
            float cx = (b == 4 || b == 9 || b == 10) ? 1.0f
                     : ((b == 6 || b == 8 || b == 11) ? -1.0f : 0.0f);
            float cy = (b == 7 || b == 8 || b == 9) ? 1.0f
                     : ((b == 5 || b == 10 || b == 11) ? -1.0f : 0.0f);
            float extra0 = (b >= 4) ? (FLUXF * (cx * dx + cy * dy) + WC0VF) : 0.0f;
            a_e = ad + extra0 - f;
            c_e = (b >= 4) ? (-0.001f * q) : 0.0f;
        }
        acc[1] += a_e * a_e;
        acc[2] += a_e * c_e;
        acc[3] += c_e * c_e;

        float wm  = (b > 3) ? 1.0f : 0.0f;
        float wcb = wm * wss[k];
        float aw  = WC0VF * wm - wcb;
        acc[0] += wcb;
        acc[4] += aw * aw;
        acc[5] += aw * q;
        acc[6] += q * q;
    }

    #pragma unroll
    for (int off = 32; off > 0; off >>= 1) {
        #pragma unroll
        for (int s = 0; s < 7; s++) acc[s] += __shfl_down(acc[s], off, 64);
    }
    __shared__ float red[2][7];
    __shared__ int slast;
    int lane = threadIdx.x & 63, wid = threadIdx.x >> 6;
    if (lane == 0) {
        #pragma unroll
        for (int s = 0; s < 7; s++) red[wid][s] = acc[s];
    }
    __syncthreads();
    if (threadIdx.x == 0) {
        #pragma unroll
        for (int s = 0; s < 7; s++)
            ws[s * NB_ + blockIdx.x] = red[0][s] + red[1][s];
        __threadfence();                                   // publish partials
        unsigned t = atomicAdd((unsigned*)(ws + 7 * NB_), 1u);
        slast = (t == NB_ - 1u) ? 1 : 0;
    }
    __syncthreads();

    if (slast) {                      // last block: final reduction
        __threadfence();              // acquire all published partials
        __shared__ float sred[7][2];
        #pragma unroll
        for (int s = 0; s < 7; s++) {
            float a = 0.0f;
            for (int tt = tid; tt < NB_ / 4; tt += TPB_) {
                float4 x = *(const float4*)(ws + s * NB_ + (tt << 2));
                a += (x.x + x.y) + (x.z + x.w);
            }
            #pragma unroll
            for (int off = 32; off > 0; off >>= 1) a += __shfl_down(a, off, 64);
            if (lane == 0) sred[s][wid] = a;
        }
        __syncthreads();
        if (tid == 0) {
            float S[7];
            #pragma unroll
            for (int s = 0; s < 7; s++) S[s] = sred[s][0] + sred[s][1];
            float mean_wc = S[0] * (1.0f / (float)HW_);
            float p = POROUS_K * sqrtf(mean_wc / WC0VF);
            float energy = S[1] + 2.0f * p * S[2] + p * p * S[3];
            float wcl    = S[4] - 2.0f * p * S[5] + p * p * S[6];
            out[0] = (energy + wcl) * (1.0f / (float)HW_);
        }
    }
}

extern "C" void kernel_launch(void* const* d_in, const int* in_sizes, int n_in,
                              void* d_out, int out_size, void* d_ws, size_t ws_size,
                              hipStream_t stream) {
    const int*   layout   = (const int*)d_in[0];
    const float* heat_ini = (const float*)d_in[1];
    const float* wc       = (const float*)d_in[2];
    const float* heat     = (const float*)d_in[3];
    const float* flow     = (const float*)d_in[4];
    float* out = (float*)d_out;    // [loss(1), heat_bc(HW), eq_mask(HW)]
    float* ws  = (float*)d_ws;     // 7*NB_ partials + [7*NB_] ticket counter

    float* out_hb = out + 1;
    float* out_eq = out + 1 + HW_;

    hipMemsetAsync(ws + 7 * NB_, 0, sizeof(unsigned), stream);  // ticket = 0
    k_main<<<NB_, TPB_, 0, stream>>>(layout, heat_ini, wc, heat, flow,
                                     out_hb, out_eq, ws, out);
}

// Round 7
// 113.132 us; speedup vs baseline: 1.6396x; 1.6396x over previous
//
#include <hip/hip_runtime.h>
#include <math.h>

#define H_ 1024
#define W_ 2048
#define HW_ (H_ * W_)
#define NB_ 2048                           // half-row per block
#define TPB_ 128
#define HALF_ 1024

#define FLUXF     0.87890625f              // 300*(6/2048)
#define F_FACT    0.002574920654296875f    // 300*(6/2048)^2
#define WC0VF     65.96910698f             // 651.83*202.412*0.001/2
#define POROUS_K  0.521986224f             // C1*C2*C4*CT

// b after the sequential .at[].set() chain (later writes win):
//   b[0,:]=3, b[-1,:]=3 ; b[:,-1]=3 ; b[:,1]=0 ; b[1,1:]=0, b[-2,1:]=0 (j>=1!)
__device__ __forceinline__ int fix_b(int raw, int i, int j) {
    if (i == 0 || i == H_ - 1) return 3;
    if (j == W_ - 1) return 3;
    if (j == 1) return 0;
    if ((i == 1 || i == H_ - 2) && j >= 1) return 0;
    return raw;
}

// Half-row per block, 8 px/thread. Moments (quadratic-in-porous split):
//  s0=sum(wc_bc) s1=sum(a^2) s2=sum(a*c) s3=sum(c^2)
//  s4=sum(aw^2)  s5=sum(aw*q) s6=sum(q^2);  e=a+p*c, w=aw-p*q.
// NO grid-wide atomics (same-address atomics serialize ~30ns each: round-6
// regression). Per-block partials -> tiny k_final.
__global__ __launch_bounds__(TPB_)
void k_main(const int* __restrict__ layout, const float* __restrict__ heat_ini,
            const float* __restrict__ wc, const float* __restrict__ heat,
            const float* __restrict__ flow, float* __restrict__ out_hb,
            float* __restrict__ out_eq, float* __restrict__ ws) {
    // XCD-strip swizzle: XCD x owns rows [x*128, (x+1)*128).
    const int virt = ((blockIdx.x & 7) << 8) | (blockIdx.x >> 3);
    const int i    = virt >> 1;
    const int jb0  = (virt & 1) * HALF_;
    const int tid  = threadIdx.x;
    const int lj   = tid << 3;
    const int jb   = jb0 + lj;
    const int im = (i == 0) ? 1 : i - 1;
    const int ip = (i == H_ - 1) ? H_ - 2 : i + 1;
    const int* L1 = layout + HW_;
    const int base  = i * W_ + jb;
    const int baseu = im * W_ + jb;
    const int based = ip * W_ + jb;

    int4   bc0 = *(const int4*)(L1 + base),      bc1 = *(const int4*)(L1 + base + 4);
    int4   bu0 = *(const int4*)(L1 + baseu),     bu1 = *(const int4*)(L1 + baseu + 4);
    int4   bd0 = *(const int4*)(L1 + based),     bd1 = *(const int4*)(L1 + based + 4);
    int4   g0  = *(const int4*)(layout + base),  g1  = *(const int4*)(layout + base + 4);
    float4 hc0 = *(const float4*)(heat + base),  hc1 = *(const float4*)(heat + base + 4);
    float4 hu0 = *(const float4*)(heat + baseu), hu1 = *(const float4*)(heat + baseu + 4);
    float4 hd0 = *(const float4*)(heat + based), hd1 = *(const float4*)(heat + based + 4);
    float4 hi0 = *(const float4*)(heat_ini + base), hi1 = *(const float4*)(heat_ini + base + 4);
    float4 w0  = *(const float4*)(wc + base),    w1  = *(const float4*)(wc + base + 4);
    float4 u0  = *(const float4*)(flow + base),  u1  = *(const float4*)(flow + base + 4);
    float4 v0  = *(const float4*)(flow + HW_ + base), v1 = *(const float4*)(flow + HW_ + base + 4);

    // Interior tile 16B-aligned; halos in separate scalars (no misaligned
    // float4 LDS stores -> no bank-conflict storm).
    __shared__ float shb[HALF_];
    __shared__ float halo2[2];             // [0]=left of jb0, [1]=right
    if (tid == 0) {
        float hv = 0.0f;
        if (jb0 != 0) {
            int j = jb0 - 1;
            hv = (fix_b(L1[i * W_ + j], i, j) != 1) ? heat[i * W_ + j] : 0.0f;
        }
        halo2[0] = hv;
    }
    if (tid == TPB_ - 1) {
        float hv = 0.0f;
        if (jb0 + HALF_ < W_) {
            int j = jb0 + HALF_;
            hv = (fix_b(L1[i * W_ + j], i, j) != 1) ? heat[i * W_ + j] : 0.0f;
        }
        halo2[1] = hv;
    }

    int   bcs[8] = {bc0.x,bc0.y,bc0.z,bc0.w, bc1.x,bc1.y,bc1.z,bc1.w};
    int   bus[8] = {bu0.x,bu0.y,bu0.z,bu0.w, bu1.x,bu1.y,bu1.z,bu1.w};
    int   bds[8] = {bd0.x,bd0.y,bd0.z,bd0.w, bd1.x,bd1.y,bd1.z,bd1.w};
    int   gs[8]  = {g0.x,g0.y,g0.z,g0.w, g1.x,g1.y,g1.z,g1.w};
    float hcs[8] = {hc0.x,hc0.y,hc0.z,hc0.w, hc1.x,hc1.y,hc1.z,hc1.w};
    float hus[8] = {hu0.x,hu0.y,hu0.z,hu0.w, hu1.x,hu1.y,hu1.z,hu1.w};
    float hds[8] = {hd0.x,hd0.y,hd0.z,hd0.w, hd1.x,hd1.y,hd1.z,hd1.w};
    float his[8] = {hi0.x,hi0.y,hi0.z,hi0.w, hi1.x,hi1.y,hi1.z,hi1.w};
    float wss[8] = {w0.x,w0.y,w0.z,w0.w, w1.x,w1.y,w1.z,w1.w};
    float us[8]  = {u0.x,u0.y,u0.z,u0.w, u1.x,u1.y,u1.z,u1.w};
    float vs[8]  = {v0.x,v0.y,v0.z,v0.w, v1.x,v1.y,v1.z,v1.w};

    int   bfix[8];
    float hb8[8], oeqs[8];
    #pragma unroll
    for (int k = 0; k < 8; k++) {
        int b = fix_b(bcs[k], i, jb + k);
        bfix[k] = b;
        hb8[k]  = (b != 1) ? hcs[k] : 0.0f;
        oeqs[k] = (b == 1) ? 0.0f : (float)b;
    }
    *(float4*)(shb + lj)     = make_float4(hb8[0], hb8[1], hb8[2], hb8[3]);
    *(float4*)(shb + lj + 4) = make_float4(hb8[4], hb8[5], hb8[6], hb8[7]);
    *(float4*)(out_hb + base)     = make_float4(hb8[0], hb8[1], hb8[2], hb8[3]);
    *(float4*)(out_hb + base + 4) = make_float4(hb8[4], hb8[5], hb8[6], hb8[7]);
    *(float4*)(out_eq + base)     = make_float4(oeqs[0], oeqs[1], oeqs[2], oeqs[3]);
    *(float4*)(out_eq + base + 4) = make_float4(oeqs[4], oeqs[5], oeqs[6], oeqs[7]);
    __syncthreads();

    float acc[7] = {0.f,0.f,0.f,0.f,0.f,0.f,0.f};
    #pragma unroll
    for (int k = 0; k < 8; k++) {
        int j = jb + k;
        int b = bfix[k];
        float hl = (k == 0) ? ((lj == 0) ? halo2[0] : shb[lj - 1]) : hb8[k - 1];
        float hr = (k == 7) ? ((lj == HALF_ - 8) ? halo2[1] : shb[lj + 8]) : hb8[k + 1];
        float dx = (j == 0 || j == W_ - 1) ? 0.0f : 0.5f * (hr - hl);
        float hbu = (fix_b(bus[k], im, j) != 1) ? hus[k] : 0.0f;
        float hbd = (fix_b(bds[k], ip, j) != 1) ? hds[k] : 0.0f;
        float dy = 0.5f * (hbd - hbu);                  // auto-0 at i=0/H-1

        float ad = his[k] - 0.001f * (us[k] * dx + vs[k] * dy);

        float t  = hb8[k] + 273.15f;
        float t2 = t * t, t3 = t2 * t;
        float cp_a = (28.11f + 0.001967f * t + 4.802e-6f * t2 - 1.966e-9f * t3)
                     * (1000.0f / 28.97f);
        float cp_v = (32.24f + 0.001923f * t + 1.055e-5f * t2 - 3.595e-9f * t3)
                     * (1000.0f / 18.015f);
        float P_v = __expf(23.2f - __fdividef(3816.4f, t - 46.1f));
        float x_v = 0.62198f * __fdividef(P_v, 101325.0f - P_v);
        float q = __fdividef(300.0f, cp_a + cp_v * 0.00725f) * (x_v - 0.00725f);

        float f = (i == 0 || i == H_ - 1) ? 0.0f
                  : fabsf((float)gs[k] - 1.0f) * F_FACT;

        float a_e, c_e;
        if (b == 1) {
            a_e = -f; c_e = 0.0f;
        } else {
            float cx = (b == 4 || b == 9 || b == 10) ? 1.0f
                     : ((b == 6 || b == 8 || b == 11) ? -1.0f : 0.0f);
            float cy = (b == 7 || b == 8 || b == 9) ? 1.0f
                     : ((b == 5 || b == 10 || b == 11) ? -1.0f : 0.0f);
            float extra0 = (b >= 4) ? (FLUXF * (cx * dx + cy * dy) + WC0VF) : 0.0f;
            a_e = ad + extra0 - f;
            c_e = (b >= 4) ? (-0.001f * q) : 0.0f;
        }
        acc[1] += a_e * a_e;
        acc[2] += a_e * c_e;
        acc[3] += c_e * c_e;

        float wm  = (b > 3) ? 1.0f : 0.0f;
        float wcb = wm * wss[k];
        float aw  = WC0VF * wm - wcb;
        acc[0] += wcb;
        acc[4] += aw * aw;
        acc[5] += aw * q;
        acc[6] += q * q;
    }

    #pragma unroll
    for (int off = 32; off > 0; off >>= 1) {
        #pragma unroll
        for (int s = 0; s < 7; s++) acc[s] += __shfl_down(acc[s], off, 64);
    }
    __shared__ float red[2][7];
    int lane = threadIdx.x & 63, wid = threadIdx.x >> 6;
    if (lane == 0) {
        #pragma unroll
        for (int s = 0; s < 7; s++) red[wid][s] = acc[s];
    }
    __syncthreads();
    if (threadIdx.x == 0) {
        #pragma unroll
        for (int s = 0; s < 7; s++)
            ws[s * NB_ + blockIdx.x] = red[0][s] + red[1][s];
    }
}

// Reduce NB_ partials per moment (2x float4 per thread), finish quadratics.
__global__ __launch_bounds__(256)
void k_final(const float* __restrict__ ws, float* __restrict__ out) {
    __shared__ float sred[7][4];
    int tid = threadIdx.x;
    #pragma unroll
    for (int s = 0; s < 7; s++) {
        float4 x = *(const float4*)(ws + s * NB_ + (tid << 3));
        float4 y = *(const float4*)(ws + s * NB_ + (tid << 3) + 4);
        float a = (x.x + x.y + x.z + x.w) + (y.x + y.y + y.z + y.w);
        #pragma unroll
        for (int off = 32; off > 0; off >>= 1) a += __shfl_down(a, off, 64);
        if ((tid & 63) == 0) sred[s][tid >> 6] = a;
    }
    __syncthreads();
    if (tid == 0) {
        float S[7];
        #pragma unroll
        for (int s = 0; s < 7; s++)
            S[s] = sred[s][0] + sred[s][1] + sred[s][2] + sred[s][3];
        float mean_wc = S[0] * (1.0f / (float)HW_);
        float p = POROUS_K * sqrtf(mean_wc / WC0VF);
        float energy = S[1] + 2.0f * p * S[2] + p * p * S[3];
        float wcl    = S[4] - 2.0f * p * S[5] + p * p * S[6];
        out[0] = (energy + wcl) * (1.0f / (float)HW_);
    }
}

extern "C" void kernel_launch(void* const* d_in, const int* in_sizes, int n_in,
                              void* d_out, int out_size, void* d_ws, size_t ws_size,
                              hipStream_t stream) {
    const int*   layout   = (const int*)d_in[0];
    const float* heat_ini = (const float*)d_in[1];
    const float* wc       = (const float*)d_in[2];
    const float* heat     = (const float*)d_in[3];
    const float* flow     = (const float*)d_in[4];
    float* out = (float*)d_out;    // [loss(1), heat_bc(HW), eq_mask(HW)]
    float* ws  = (float*)d_ws;     // 7 * NB_ block partials (SoA)

    float* out_hb = out + 1;
    float* out_eq = out + 1 + HW_;

    k_main<<<NB_, TPB_, 0, stream>>>(layout, heat_ini, wc, heat, flow,
                                     out_hb, out_eq, ws);
    k_final<<<1, 256, 0, stream>>>(ws, out);
}